// Round 14
// baseline (2986.456 us; speedup 1.0000x reference)
//
#include <hip/hip_runtime.h>

#define BATCH 64
#define LEN   2048
#define NIN   128
#define NH    256

typedef float f32x4 __attribute__((ext_vector_type(4)));
typedef float f32x2 __attribute__((ext_vector_type(2)));

// ---------------------------------------------------------------------------
// FROZEN ARITHMETIC (R7: absmax == 0.0). Do not touch:
//  - dots: single-accumulator, k-ascending fmaf chains from 0
//  - pre = (xw + acc) + bias, left-assoc, no contraction
//  - tanh = EmitFastTanh(with_fma=true): clamp ±7.99881172180175781,
//    fmaf Horner, IEEE f32 divide, |x|<0.0004 passthrough
// ---------------------------------------------------------------------------
__device__ __forceinline__ float tanh_xla_fma_f32(float x) {
  const float kClamp = 7.99881172180175781f;
  float xc = fmaxf(x, -kClamp);
  xc = fminf(xc, kClamp);
  float x2 = xc * xc;
  float num = fmaf(x2, -2.76076847742355e-16f, 2.00018790482477e-13f);
  num = fmaf(x2, num, -8.60467152213735e-11f);
  num = fmaf(x2, num, 5.12229709037114e-08f);
  num = fmaf(x2, num, 1.48572235717979e-05f);
  num = fmaf(x2, num, 6.37261928875436e-04f);
  num = fmaf(x2, num, 4.89352455891786e-03f);
  num = xc * num;
  float den = fmaf(x2, 1.19825839466702e-06f, 1.18534705686654e-04f);
  den = fmaf(x2, den, 2.26843463243900e-03f);
  den = fmaf(x2, den, 4.89352518554385e-03f);
  float r = num / den;
  return (fabsf(x) < 0.0004f) ? x : r;
}

#define PINV(v) asm("" : "+v"(v));

// Hand-scheduled quad blocks (R12 lesson: readlane->fma adjacency pays the
// VALU-writes-SGPR hazard 256x/step; RA-demoted quads insert unscheduled
// accvgpr copies). NAMED asm operands (R13 lesson: clang appends "+"-tied
// inputs at the END of the number space — positional %N off-by-one traps).
//   V-quad: [rl x4 -> fma x4]                  (rl->fma distance >=3)
//   A-quad: [agpr_read x4 -> rl x4 -> fma x4]  (agpr->fma distance 8)
// fma operand order inside each block == frozen k-ascending chain.

#define REPV48(M) M(0) M(1) M(2) M(3) M(4) M(5) M(6) M(7) \
  M(8) M(9) M(10) M(11) M(12) M(13) M(14) M(15) \
  M(16) M(17) M(18) M(19) M(20) M(21) M(22) M(23) \
  M(24) M(25) M(26) M(27) M(28) M(29) M(30) M(31) \
  M(32) M(33) M(34) M(35) M(36) M(37) M(38) M(39) \
  M(40) M(41) M(42) M(43) M(44) M(45) M(46) M(47)
#define REPA16(M) M(48) M(49) M(50) M(51) M(52) M(53) M(54) M(55) \
  M(56) M(57) M(58) M(59) M(60) M(61) M(62) M(63)
#define REPX32(M) M(0) M(1) M(2) M(3) M(4) M(5) M(6) M(7) \
  M(8) M(9) M(10) M(11) M(12) M(13) M(14) M(15) \
  M(16) M(17) M(18) M(19) M(20) M(21) M(22) M(23) \
  M(24) M(25) M(26) M(27) M(28) M(29) M(30) M(31)

#define WQ_DECL(n) f32x4 wq##n;
#define WQ_LOAD(n) wq##n = wrow[n]; PINV(wq##n)
#define AQ_DECL(n) float aq##n##x, aq##n##y, aq##n##z, aq##n##w;
#define AQ_LOAD(n) { f32x4 v = wrow[n]; \
  asm("v_accvgpr_write_b32 %0, %1" : "=a"(aq##n##x) : "v"(v.x)); \
  asm("v_accvgpr_write_b32 %0, %1" : "=a"(aq##n##y) : "v"(v.y)); \
  asm("v_accvgpr_write_b32 %0, %1" : "=a"(aq##n##z) : "v"(v.z)); \
  asm("v_accvgpr_write_b32 %0, %1" : "=a"(aq##n##w) : "v"(v.w)); }

// V-quad block: h[4n..4n+3] = lane n of hq.x/y/z/w; weights in VGPRs.
#define STEPV(n) { float t0, t1, t2, t3; \
  asm volatile( \
    "v_readlane_b32 %[s0], %[hx], %[ln]\n\t" \
    "v_readlane_b32 %[s1], %[hy], %[ln]\n\t" \
    "v_readlane_b32 %[s2], %[hz], %[ln]\n\t" \
    "v_readlane_b32 %[s3], %[hw], %[ln]\n\t" \
    "v_fma_f32 %[a], %[s0], %[w0], %[a]\n\t" \
    "v_fma_f32 %[a], %[s1], %[w1], %[a]\n\t" \
    "v_fma_f32 %[a], %[s2], %[w2], %[a]\n\t" \
    "v_fma_f32 %[a], %[s3], %[w3], %[a]" \
    : [a]"+v"(acc), [s0]"=&s"(t0), [s1]"=&s"(t1), [s2]"=&s"(t2), [s3]"=&s"(t3) \
    : [hx]"v"(hq.x), [hy]"v"(hq.y), [hz]"v"(hq.z), [hw]"v"(hq.w), [ln]"i"(n), \
      [w0]"v"(wq##n.x), [w1]"v"(wq##n.y), [w2]"v"(wq##n.z), [w3]"v"(wq##n.w)); }

// A-quad block: weights in AGPRs, copied in-block 8 instrs ahead of use.
#define STEPA(n) { float w0_, w1_, w2_, w3_, t0, t1, t2, t3; \
  asm volatile( \
    "v_accvgpr_read_b32 %[w0], %[ax]\n\t" \
    "v_accvgpr_read_b32 %[w1], %[ay]\n\t" \
    "v_accvgpr_read_b32 %[w2], %[az]\n\t" \
    "v_accvgpr_read_b32 %[w3], %[aw]\n\t" \
    "v_readlane_b32 %[s0], %[hx], %[ln]\n\t" \
    "v_readlane_b32 %[s1], %[hy], %[ln]\n\t" \
    "v_readlane_b32 %[s2], %[hz], %[ln]\n\t" \
    "v_readlane_b32 %[s3], %[hw], %[ln]\n\t" \
    "v_fma_f32 %[a], %[s0], %[w0], %[a]\n\t" \
    "v_fma_f32 %[a], %[s1], %[w1], %[a]\n\t" \
    "v_fma_f32 %[a], %[s2], %[w2], %[a]\n\t" \
    "v_fma_f32 %[a], %[s3], %[w3], %[a]" \
    : [a]"+v"(acc), [w0]"=&v"(w0_), [w1]"=&v"(w1_), [w2]"=&v"(w2_), [w3]"=&v"(w3_), \
      [s0]"=&s"(t0), [s1]"=&s"(t1), [s2]"=&s"(t2), [s3]"=&s"(t3) \
    : [hx]"v"(hq.x), [hy]"v"(hq.y), [hz]"v"(hq.z), [hw]"v"(hq.w), \
      [ax]"a"(aq##n##x), [ay]"a"(aq##n##y), [az]"a"(aq##n##z), [aw]"a"(aq##n##w), \
      [ln]"i"(n)); }

// xw block: x[4n..4n+3] = lanes 2n,2n,2n+1,2n+1 of xv.x/.y; weights VGPR.
#define XSTEP(n) { float t0, t1, t2, t3; \
  asm volatile( \
    "v_readlane_b32 %[s0], %[vx], %[l0]\n\t" \
    "v_readlane_b32 %[s1], %[vy], %[l0]\n\t" \
    "v_readlane_b32 %[s2], %[vx], %[l1]\n\t" \
    "v_readlane_b32 %[s3], %[vy], %[l1]\n\t" \
    "v_fma_f32 %[a], %[s0], %[w0], %[a]\n\t" \
    "v_fma_f32 %[a], %[s1], %[w1], %[a]\n\t" \
    "v_fma_f32 %[a], %[s2], %[w2], %[a]\n\t" \
    "v_fma_f32 %[a], %[s3], %[w3], %[a]" \
    : [a]"+v"(acc), [s0]"=&s"(t0), [s1]"=&s"(t1), [s2]"=&s"(t2), [s3]"=&s"(t3) \
    : [vx]"v"(xv.x), [vy]"v"(xv.y), [l0]"i"(2*(n)), [l1]"i"(2*(n)+1), \
      [w0]"v"(wq##n.x), [w1]"v"(wq##n.y), [w2]"v"(wq##n.z), [w3]"v"(wq##n.w)); }

// ---------------------------------------------------------------------------
// Kernel A: xw[l][b][h] = sum_i x[b][l][i] * Wx[h][i]
// Coalesced dwordx2/lane per row; broadcast via readlane; 32 V-quad blocks.
// ---------------------------------------------------------------------------
constexpr int LC = 128;   // l-positions per block

__global__ __launch_bounds__(256, 2)
void xw_kernel(const float* __restrict__ x, const float* __restrict__ Wx,
               float* __restrict__ out) {
  const int j    = threadIdx.x;
  const int lane = j & 63;
  const int b    = blockIdx.x & (BATCH - 1);
  const int lt   = blockIdx.x >> 6;

  const f32x4* wrow = (const f32x4*)&Wx[(size_t)j * NIN];
  REPX32(WQ_DECL)
  REPX32(WQ_LOAD)

  const float* xr = x + ((size_t)b * LEN + (size_t)lt * LC) * NIN;
  float* op = out + ((size_t)lt * LC * BATCH + b) * NH + j;

  f32x2 xv = *(const f32x2*)(xr + 2 * lane);       // row 0, coalesced
  for (int ll = 0; ll < LC; ++ll) {
    const int ln = (ll + 1 < LC) ? (ll + 1) : ll;
    f32x2 xnext = *(const f32x2*)(xr + (size_t)ln * NIN + 2 * lane);
    float acc = 0.0f;
    REPX32(XSTEP)
    op[(size_t)ll * BATCH * NH] = acc;
    xv = xnext;
  }
}

// ---------------------------------------------------------------------------
// Kernel B: recurrence. One batch/block, 256 threads (1 wave/SIMD).
// Weights: 48 V-quads (192 arch VGPR) + 16 A-quads (64 AGPR). Per step: ONE
// coalesced ds_read_b128/wave -> hq, then 64 hand-scheduled quad blocks.
// lgkmcnt-only barrier (global store stays in flight).
// ---------------------------------------------------------------------------
__global__ __launch_bounds__(256, 1)
void rnn_kernel(const float* __restrict__ Wh, const float* __restrict__ bh,
                const float* __restrict__ h0, float* __restrict__ io) {
  const int b    = blockIdx.x;
  const int j    = threadIdx.x;
  const int lane = j & 63;

  __shared__ __align__(16) float hbuf[2][NH];

  const f32x4* wrow = (const f32x4*)&Wh[(size_t)j * NH];
  REPV48(WQ_DECL)
  REPA16(AQ_DECL)
  REPV48(WQ_LOAD)
  REPA16(AQ_LOAD)

  const float bias = bh[j];
  hbuf[0][j] = h0[b * NH + j];
  __syncthreads();

  float* p = io + (size_t)b * NH + j;
  const size_t stride = (size_t)BATCH * NH;

  float xw = p[0];
  int cur = 0;

  for (int l = 0; l < LEN; ++l) {
    const int ln = (l + 1 < LEN) ? (l + 1) : l;
    const float xw_next = p[(size_t)ln * stride];   // prefetch next xw

    const f32x4 hq = *(const f32x4*)&hbuf[cur][4 * lane];  // 1 coalesced read
    float acc = 0.0f;
    REPV48(STEPV)
    REPA16(STEPA)

    float pre;
    {
#pragma clang fp contract(off)
      pre = (xw + acc) + bias;                  // ((xw + hW) + b) order
    }
    const float hn = tanh_xla_fma_f32(pre);

    p[(size_t)l * stride] = hn;                 // fire-and-forget store
    hbuf[cur ^ 1][j] = hn;                      // publish state

    // lgkmcnt-only barrier: LDS visible, global store left in flight.
    asm volatile("s_waitcnt lgkmcnt(0)" ::: "memory");
    __builtin_amdgcn_s_barrier();
    asm volatile("" ::: "memory");

    cur ^= 1;
    xw = xw_next;
  }
}

extern "C" void kernel_launch(void* const* d_in, const int* in_sizes, int n_in,
                              void* d_out, int out_size, void* d_ws, size_t ws_size,
                              hipStream_t stream) {
  // Resolve inputs BY SIZE (all element counts distinct).
  const float* x  = (const float*)d_in[0];  // 16777216
  const float* h0 = (const float*)d_in[1];  // 16384
  const float* Wx = (const float*)d_in[2];  // 32768
  const float* Wh = (const float*)d_in[3];  // 65536
  const float* bh = (const float*)d_in[4];  // 256
  for (int i = 0; i < n_in; ++i) {
    switch (in_sizes[i]) {
      case 16777216: x  = (const float*)d_in[i]; break;
      case 16384:    h0 = (const float*)d_in[i]; break;
      case 32768:    Wx = (const float*)d_in[i]; break;
      case 65536:    Wh = (const float*)d_in[i]; break;
      case 256:      bh = (const float*)d_in[i]; break;
      default: break;
    }
  }
  float* out = (float*)d_out;               // [2048, 64, 256] f32

  xw_kernel<<<dim3((LEN / LC) * BATCH), dim3(256), 0, stream>>>(x, Wx, out);
  rnn_kernel<<<dim3(BATCH), dim3(256), 0, stream>>>(Wh, bh, h0, out);
}